// Round 10
// baseline (116.513 us; speedup 1.0000x reference)
//
#include <hip/hip_runtime.h>
#include <math.h>

// Sliding-window causal attention, B=2 H=16 N=2048 D=64 W=512, fp32 in/out.
//  swa_prep: K-blocks (stream convert) + V-blocks (conflict-free LDS transpose)
//            -> bf16 8KB-tile-blocked ws, chunk-XOR swizzled, scale folded into K.
//  swa_main: BM=128, 256 thr (4 waves x 32 rows = 2 strips). S^T operand-swap
//            flash attention, P in-lane. K/V fragments loaded from LDS ONCE per
//            (wave,tile), reused by both strips. Per-tile double buffer, grid 512
//            -> 2 blocks/CU for barrier overlap. Trunc-packed P.
// Fallback to round-4 kernel if ws_size < 16.78 MB.

#define SEQ 2048
#define HD  64
#define LDR 72

typedef short short8 __attribute__((ext_vector_type(8)));
typedef float f32x4  __attribute__((ext_vector_type(4)));
typedef int   i32x4  __attribute__((ext_vector_type(4)));

static __device__ inline unsigned short f2bf(float f){
  union{float f; unsigned u;} un; un.f=f;
  return (unsigned short)((un.u + 0x7FFFu + ((un.u>>16)&1u))>>16);
}
static __device__ inline int swz(int row){ return (row&3)|(((row>>3)&1)<<2); }

static __device__ __forceinline__ void gll16(const unsigned short* g, unsigned short* l){
  __builtin_amdgcn_global_load_lds(
    (const __attribute__((address_space(1))) unsigned int*)(const void*)g,
    (__attribute__((address_space(3))) unsigned int*)(void*)l, 16, 0, 0);
}

// ---------------- pre-pass: K-blocks stream, V-blocks transpose ----------------
__global__ __launch_bounds__(256) void swa_prep(
    const float* __restrict__ k, const float* __restrict__ v,
    unsigned short* __restrict__ Kb, unsigned short* __restrict__ Vtb)
{
  const int tid=threadIdx.x, bid=blockIdx.x;
  const float C=0.18033688011112042f;            // 0.125 * log2(e), folded into K

  if(bid<1024){
    const long tbase=(long)bid*4096;
    #pragma unroll
    for(int i=0;i<2;++i){
      int id=i*256+tid, r=id>>3, lc=id&7;
      float4 f0=*(const float4*)(k+tbase+r*64+lc*8);
      float4 f1=*(const float4*)(k+tbase+r*64+lc*8+4);
      unsigned short hh[8];
      hh[0]=f2bf(f0.x*C); hh[1]=f2bf(f0.y*C); hh[2]=f2bf(f0.z*C); hh[3]=f2bf(f0.w*C);
      hh[4]=f2bf(f1.x*C); hh[5]=f2bf(f1.y*C); hh[6]=f2bf(f1.z*C); hh[7]=f2bf(f1.w*C);
      *(uint4*)(Kb+tbase+r*64+(long)((lc^swz(r))*8))=*(uint4*)hh;
    }
  } else {
    __shared__ unsigned short Vs[64*68];
    const long tbase=(long)(bid-1024)*4096;
    #pragma unroll
    for(int i=0;i<2;++i){
      int id=i*256+tid, r=id>>3, c=id&7;
      int phys=(c^(r>>3))&7;
      float4 f0=*(const float4*)(v+tbase+r*64+c*8);
      float4 f1=*(const float4*)(v+tbase+r*64+c*8+4);
      ushort4 a,b;
      a.x=f2bf(f0.x); a.y=f2bf(f0.y); a.z=f2bf(f0.z); a.w=f2bf(f0.w);
      b.x=f2bf(f1.x); b.y=f2bf(f1.y); b.z=f2bf(f1.z); b.w=f2bf(f1.w);
      *(ushort4*)&Vs[r*68+phys*8]  =a;
      *(ushort4*)&Vs[r*68+phys*8+4]=b;
    }
    __syncthreads();
    #pragma unroll
    for(int i=0;i<2;++i){
      int id=i*256+tid, d=id>>3, lc=id&7;
      unsigned short t8[8];
      #pragma unroll
      for(int e=0;e<8;++e){
        int key=lc*8+e;
        int phys=((d>>3)^lc)&7;
        t8[e]=Vs[key*68 + phys*8 + (d&7)];
      }
      *(uint4*)(Vtb+tbase+d*64+(long)((lc^swz(d))*8))=*(uint4*)t8;
    }
  }
}

// -------- main: BM=128, 4 waves x 2 strips, in-lane-P flash attention --------
__global__ __launch_bounds__(256) void swa_main(
    const float* __restrict__ q,
    const unsigned short* __restrict__ Kb,
    const unsigned short* __restrict__ Vtb,
    float* __restrict__ out)
{
  __shared__ unsigned short Ks[2][4096];
  __shared__ unsigned short Vsh[2][4096];

  const int tid=threadIdx.x, bid=blockIdx.x;
  const int mt=bid&15, bh=bid>>4, m0=mt*128;
  const long base=(long)bh*SEQ*HD;
  const int wv=tid>>6, lane=tid&63, quad=lane>>4, l16=lane&15;
  const int qr0=m0+wv*32+l16;               // strip0 query row (this lane)

  // Q B-fragments per strip (scale folded into Kb)
  short8 qa[2][2];
  #pragma unroll
  for(int s=0;s<2;++s){
    const float* qp=q+base+(long)(qr0+s*16)*HD+quad*8;
    #pragma unroll
    for(int kk=0;kk<2;++kk){
      float4 f0=*(const float4*)(qp+kk*32);
      float4 f1=*(const float4*)(qp+kk*32+4);
      short8 a;
      a[0]=(short)f2bf(f0.x); a[1]=(short)f2bf(f0.y);
      a[2]=(short)f2bf(f0.z); a[3]=(short)f2bf(f0.w);
      a[4]=(short)f2bf(f1.x); a[5]=(short)f2bf(f1.y);
      a[6]=(short)f2bf(f1.z); a[7]=(short)f2bf(f1.w);
      qa[s][kk]=a;
    }
  }

  // Per-lane constant LDS offsets (R6-verified in-lane-P fragment mapping)
  const int rbase=8*(l16>>2)+(l16&3);
  const int swk=(l16&3)|(((l16>>2)&1)<<2);   // swz(ka row)
  const int swv=(l16&3)|(((l16>>3)&1)<<2);   // swz(vb row)
  int kaoff[2][4], vboff[2][4];
  #pragma unroll
  for(int kk=0;kk<2;++kk){
    #pragma unroll
    for(int nt=0;nt<4;++nt)
      kaoff[kk][nt]=(rbase+(nt&1)*4+(nt>>1)*32)*64+(((quad+4*kk)^swk)*8);
    #pragma unroll
    for(int dt=0;dt<4;++dt)
      vboff[kk][dt]=(dt*16+l16)*64+(((quad+4*kk)^swv)*8);
  }

  const unsigned short* Kt=Kb +(long)bh*32*4096;
  const unsigned short* Vt=Vtb+(long)bh*32*4096;
  const int seg=tid*8;   // 16B/thread; 256 thr = 4KB per gll16 round

  f32x4 oacc[2][4];
  #pragma unroll
  for(int s=0;s<2;++s)
    #pragma unroll
    for(int dt=0;dt<4;++dt) oacc[s][dt]=(f32x4){0.f,0.f,0.f,0.f};
  float lrun[2]={0.f,0.f};

  const int Tb =2*mt+1;
  const int Tlo=(2*mt>8)?(2*mt-8):0;
  const int myTb=2*mt+(wv>>1);               // both strips in this 64-row half
  const bool clip=(myTb>=8);
  const int myTlo=clip?(myTb-8):0;

  // stage first tile -> buf0
  {
    const long o=(long)Tlo*4096;
    gll16(Kt+o+seg,      &Ks[0][seg]);
    gll16(Kt+o+2048+seg, &Ks[0][2048+seg]);
    gll16(Vt+o+seg,      &Vsh[0][seg]);
    gll16(Vt+o+2048+seg, &Vsh[0][2048+seg]);
  }
  __syncthreads();

  for(int t=Tlo;t<=Tb;++t){
    const int buf=(t-Tlo)&1;
    if(t<Tb){
      const long o=(long)(t+1)*4096;
      gll16(Kt+o+seg,      &Ks[buf^1][seg]);
      gll16(Kt+o+2048+seg, &Ks[buf^1][2048+seg]);
      gll16(Vt+o+seg,      &Vsh[buf^1][seg]);
      gll16(Vt+o+2048+seg, &Vsh[buf^1][2048+seg]);
    }
    if(t>=myTlo && t<=myTb){                 // wave-uniform skip (1 idle tile/wave)
      // --- load K/V fragments ONCE, reuse for both strips ---
      short8 ka[2][4], vb[4][2];
      #pragma unroll
      for(int kk=0;kk<2;++kk)
        #pragma unroll
        for(int nt=0;nt<4;++nt)
          ka[kk][nt]=*(const short8*)&Ks[buf][kaoff[kk][nt]];
      #pragma unroll
      for(int dt=0;dt<4;++dt)
        #pragma unroll
        for(int kk=0;kk<2;++kk)
          vb[dt][kk]=*(const short8*)&Vsh[buf][vboff[kk][dt]];

      const bool msk=(t==myTb)||(clip&&t==myTlo);
      #pragma unroll
      for(int s=0;s<2;++s){
        const int qrow=qr0+s*16;
        f32x4 sacc[4];
        #pragma unroll
        for(int nt=0;nt<4;++nt) sacc[nt]=(f32x4){0.f,0.f,0.f,0.f};
        #pragma unroll
        for(int kk=0;kk<2;++kk)
          #pragma unroll
          for(int nt=0;nt<4;++nt)
            sacc[nt]=__builtin_amdgcn_mfma_f32_16x16x32_bf16(ka[kk][nt],qa[s][kk],sacc[nt],0,0,0);

        // p = exp2(s); trunc-pack pairs (P stays in-lane)
        unsigned pp[8];
        float ls=0.f;
        #pragma unroll
        for(int nt=0;nt<4;++nt){
          float e0=__builtin_amdgcn_exp2f(sacc[nt][0]);
          float e1=__builtin_amdgcn_exp2f(sacc[nt][1]);
          float e2=__builtin_amdgcn_exp2f(sacc[nt][2]);
          float e3=__builtin_amdgcn_exp2f(sacc[nt][3]);
          if(msk){
            const int kb0=t*64+8*quad+(nt&1)*4+(nt>>1)*32;
            e0=((kb0+0<=qrow)&&(kb0+0+511>=qrow))?e0:0.f;
            e1=((kb0+1<=qrow)&&(kb0+1+511>=qrow))?e1:0.f;
            e2=((kb0+2<=qrow)&&(kb0+2+511>=qrow))?e2:0.f;
            e3=((kb0+3<=qrow)&&(kb0+3+511>=qrow))?e3:0.f;
          }
          ls+=e0+e1+e2+e3;
          pp[nt*2+0]=(__float_as_uint(e1)&0xFFFF0000u)|(__float_as_uint(e0)>>16);
          pp[nt*2+1]=(__float_as_uint(e3)&0xFFFF0000u)|(__float_as_uint(e2)>>16);
        }
        lrun[s]+=ls;
        i32x4 i0={(int)pp[0],(int)pp[1],(int)pp[2],(int)pp[3]};
        i32x4 i1={(int)pp[4],(int)pp[5],(int)pp[6],(int)pp[7]};
        short8 pa0=*(short8*)&i0;
        short8 pa1=*(short8*)&i1;
        #pragma unroll
        for(int dt=0;dt<4;++dt){
          oacc[s][dt]=__builtin_amdgcn_mfma_f32_16x16x32_bf16(pa0,vb[dt][0],oacc[s][dt],0,0,0);
          oacc[s][dt]=__builtin_amdgcn_mfma_f32_16x16x32_bf16(pa1,vb[dt][1],oacc[s][dt],0,0,0);
        }
      }
    }
    __syncthreads();
  }

  // epilogue per strip: l = sum over quads; store O/l
  #pragma unroll
  for(int s=0;s<2;++s){
    float l=lrun[s];
    l+=__shfl_xor(l,16);
    l+=__shfl_xor(l,32);
    float linv=1.0f/l;
    #pragma unroll
    for(int r=0;r<4;++r){
      float lr=__shfl(linv,quad*4+r);
      const int orow=m0+wv*32+s*16+quad*4+r;
      #pragma unroll
      for(int dt=0;dt<4;++dt)
        out[base+(long)orow*HD+dt*16+l16]=oacc[s][dt][r]*lr;
    }
  }
}

// ---------------- fallback (round-4 kernel) ----------------
__global__ __launch_bounds__(256) void swa_fwd(
    const float* __restrict__ q, const float* __restrict__ k,
    const float* __restrict__ v, float* __restrict__ out)
{
  __shared__ short Qs[64*LDR];
  __shared__ short Ps[64*LDR];
  __shared__ short Ksh[2][64*LDR];
  __shared__ short Vtr[2][HD*LDR];

  const int tid=threadIdx.x, bid=blockIdx.x;
  const int mtile=bid&31, bh=bid>>5, m0=mtile*64;
  const long base=(long)bh*SEQ*HD;
  const int wv=tid>>6, lane=tid&63, quad=lane>>4, l16=lane&15;
  const int dcol=lane;

  {
    const float4* qg=(const float4*)(q+base+(long)m0*HD);
    #pragma unroll
    for(int i=0;i<4;++i){
      int idx=i*256+tid, r=idx>>4, c4=idx&15;
      float4 f=qg[idx];
      ushort4 hh; hh.x=f2bf(f.x); hh.y=f2bf(f.y); hh.z=f2bf(f.z); hh.w=f2bf(f.w);
      *(ushort4*)&Qs[r*LDR+c4*4]=hh;
    }
  }
  const int tb=mtile, tlo=(tb>8)?(tb-8):0;
  float4 kreg[4]; float vcol[4][4];
  {
    const float4* kg=(const float4*)(k+base+(long)(tlo*64)*HD);
    const float*  vg=v+base+(long)(tlo*64)*HD;
    #pragma unroll
    for(int i=0;i<4;++i) kreg[i]=kg[i*256+tid];
    #pragma unroll
    for(int g=0;g<4;++g){ int r0=wv*4+g*16;
      #pragma unroll
      for(int j=0;j<4;++j) vcol[g][j]=vg[(r0+j)*HD+dcol]; }
  }
  __syncthreads();
  short8 qa[2];
  #pragma unroll
  for(int kk=0;kk<2;++kk)
    qa[kk]=*(const short8*)&Qs[(wv*16+l16)*LDR+kk*32+quad*8];
  {
    #pragma unroll
    for(int i=0;i<4;++i){
      int idx=i*256+tid, r=idx>>4, c4=idx&15;
      float4 fk=kreg[i];
      ushort4 hk; hk.x=f2bf(fk.x); hk.y=f2bf(fk.y); hk.z=f2bf(fk.z); hk.w=f2bf(fk.w);
      *(ushort4*)&Ksh[0][r*LDR+c4*4]=hk;
    }
    #pragma unroll
    for(int g=0;g<4;++g){ int r0=wv*4+g*16;
      ushort4 hv; hv.x=f2bf(vcol[g][0]); hv.y=f2bf(vcol[g][1]);
                  hv.z=f2bf(vcol[g][2]); hv.w=f2bf(vcol[g][3]);
      *(ushort4*)&Vtr[0][dcol*LDR+r0]=hv; }
  }
  float lrun[4]={0.f,0.f,0.f,0.f};
  f32x4 oacc[4];
  #pragma unroll
  for(int dt=0;dt<4;++dt) oacc[dt]=(f32x4){0.f,0.f,0.f,0.f};
  __syncthreads();

  for(int t=tlo;t<=tb;++t){
    const int buf=(t-tlo)&1, j0=t*64;
    f32x4 sacc[4];
    #pragma unroll
    for(int nt=0;nt<4;++nt) sacc[nt]=(f32x4){0.f,0.f,0.f,0.f};
    #pragma unroll
    for(int kk=0;kk<2;++kk){
      #pragma unroll
      for(int nt=0;nt<4;++nt){
        short8 kb=*(const short8*)&Ksh[buf][(nt*16+l16)*LDR+kk*32+quad*8];
        sacc[nt]=__builtin_amdgcn_mfma_f32_16x16x32_bf16(qa[kk],kb,sacc[nt],0,0,0);
      }
    }
    if(t<tb){
      const float4* kg=(const float4*)(k+base+(long)((t+1)*64)*HD);
      const float*  vg=v+base+(long)((t+1)*64)*HD;
      #pragma unroll
      for(int i=0;i<4;++i) kreg[i]=kg[i*256+tid];
      #pragma unroll
      for(int g=0;g<4;++g){ int r0=wv*4+g*16;
        #pragma unroll
        for(int j=0;j<4;++j) vcol[g][j]=vg[(r0+j)*HD+dcol]; }
    }
    #pragma unroll
    for(int r=0;r<4;++r){
      const int grr=m0+wv*16+quad*4+r;
      #pragma unroll
      for(int nt=0;nt<4;++nt){
        const int gc=j0+nt*16+l16;
        float e=exp2f(sacc[nt][r]*0.18033688011112042f);
        float p=((gc<=grr)&&(gc>=grr-511))?e:0.f;
        lrun[r]+=p;
        Ps[(wv*16+quad*4+r)*LDR+nt*16+l16]=(short)f2bf(p);
      }
    }
    __syncthreads();
    #pragma unroll
    for(int kk=0;kk<2;++kk){
      short8 pa=*(const short8*)&Ps[(wv*16+l16)*LDR+kk*32+quad*8];
      #pragma unroll
      for(int dt=0;dt<4;++dt){
        short8 vb=*(const short8*)&Vtr[buf][(dt*16+l16)*LDR+kk*32+quad*8];
        oacc[dt]=__builtin_amdgcn_mfma_f32_16x16x32_bf16(pa,vb,oacc[dt],0,0,0);
      }
    }
    if(t<tb){
      #pragma unroll
      for(int i=0;i<4;++i){
        int idx=i*256+tid, r=idx>>4, c4=idx&15;
        float4 fk=kreg[i];
        ushort4 hk; hk.x=f2bf(fk.x); hk.y=f2bf(fk.y); hk.z=f2bf(fk.z); hk.w=f2bf(fk.w);
        *(ushort4*)&Ksh[buf^1][r*LDR+c4*4]=hk;
      }
      #pragma unroll
      for(int g=0;g<4;++g){ int r0=wv*4+g*16;
        ushort4 hv; hv.x=f2bf(vcol[g][0]); hv.y=f2bf(vcol[g][1]);
                    hv.z=f2bf(vcol[g][2]); hv.w=f2bf(vcol[g][3]);
        *(ushort4*)&Vtr[buf^1][dcol*LDR+r0]=hv; }
    }
    __syncthreads();
  }
  #pragma unroll
  for(int r=0;r<4;++r){
    float s=lrun[r];
    s+=__shfl_xor(s,1); s+=__shfl_xor(s,2); s+=__shfl_xor(s,4); s+=__shfl_xor(s,8);
    lrun[r]=(s>0.f)?(1.f/s):0.f;
  }
  #pragma unroll
  for(int r=0;r<4;++r){
    const int row=m0+wv*16+quad*4+r;
    #pragma unroll
    for(int dt=0;dt<4;++dt)
      out[base+(long)row*HD+dt*16+l16]=oacc[dt][r]*lrun[r];
  }
}

extern "C" void kernel_launch(void* const* d_in, const int* in_sizes, int n_in,
                              void* d_out, int out_size, void* d_ws, size_t ws_size,
                              hipStream_t stream) {
  (void)in_sizes; (void)n_in; (void)out_size;
  const float* q=(const float*)d_in[0];
  const float* k=(const float*)d_in[1];
  const float* v=(const float*)d_in[2];
  float* o=(float*)d_out;
  const size_t NEED = 2ull*32*2048*64*2;   // Kb + Vtb bf16 = 16.78 MB
  if (ws_size>=NEED){
    unsigned short* Kb =(unsigned short*)d_ws;
    unsigned short* Vtb=Kb+32ull*2048*64;
    hipLaunchKernelGGL(swa_prep, dim3(2048), dim3(256), 0, stream, k, v, Kb, Vtb);
    hipLaunchKernelGGL(swa_main, dim3(512),  dim3(256), 0, stream, q, Kb, Vtb, o);
  } else {
    hipLaunchKernelGGL(swa_fwd, dim3(1024), dim3(256), 0, stream, q, k, v, o);
  }
}

// Round 11
// 108.206 us; speedup vs baseline: 1.0768x; 1.0768x over previous
//
#include <hip/hip_runtime.h>

// Sliding-window causal attention, B=2 H=16 N=2048 D=64 W=512, fp32 in/out.
// SINGLE fused kernel (no workspace, no prep pass):
//   BM=128, 512 thr, 8 waves x 1 strip (R7-winning config, best measured TLP).
//   S^T operand-swap flash attention: P stays in-lane between QK and PV MFMAs
//   (no Ps LDS round-trip, no per-tile shuffles, softmax denom reduced once in
//   the epilogue). K/V staged fp32->bf16 inline into chunk-XOR-swizzled LDS
//   (conflict-free b128 reads/writes), per-tile double buffer, 1 barrier/iter.
//   Global prefetch for t+1 issued before tile-t compute to hide HBM latency.

#define SEQ 2048
#define HD  64

typedef short short8 __attribute__((ext_vector_type(8)));
typedef float f32x4  __attribute__((ext_vector_type(4)));
typedef int   i32x4  __attribute__((ext_vector_type(4)));

static __device__ inline unsigned short f2bf(float f){
  union{float f; unsigned u;} un; un.f=f;
  return (unsigned short)((un.u + 0x7FFFu + ((un.u>>16)&1u))>>16);
}
static __device__ inline int swz(int row){ return (row&3)|(((row>>3)&1)<<2); }

__global__ __launch_bounds__(512) void swa_fused(
    const float* __restrict__ q, const float* __restrict__ k,
    const float* __restrict__ v, float* __restrict__ out)
{
  __shared__ unsigned short Ks[2][4096];    // [key(64)][d(64)] bf16, chunk-swizzled
  __shared__ unsigned short Vsh[2][4096];   // [d(64)][key(64)] bf16, chunk-swizzled

  const int tid=threadIdx.x, bid=blockIdx.x;
  const int mt=bid&15, bh=bid>>4, m0=mt*128;
  const long base=(long)bh*SEQ*HD;
  const int wv=tid>>6, lane=tid&63, quad=lane>>4, l16=lane&15;
  const int qrow=m0+wv*16+l16;
  const int h=wv>>2;                        // block half (rows 0-63 / 64-127)

  // ---- Q B-fragment, softmax scale folded here (Q loaded once per block) ----
  short8 qa[2];
  {
    const float C=0.18033688011112042f;     // 0.125 * log2(e)
    const float* qp=q+base+(long)qrow*HD+quad*8;
    #pragma unroll
    for(int kk=0;kk<2;++kk){
      float4 f0=*(const float4*)(qp+kk*32);
      float4 f1=*(const float4*)(qp+kk*32+4);
      short8 a;
      a[0]=(short)f2bf(f0.x*C); a[1]=(short)f2bf(f0.y*C);
      a[2]=(short)f2bf(f0.z*C); a[3]=(short)f2bf(f0.w*C);
      a[4]=(short)f2bf(f1.x*C); a[5]=(short)f2bf(f1.y*C);
      a[6]=(short)f2bf(f1.z*C); a[7]=(short)f2bf(f1.w*C);
      qa[kk]=a;
    }
  }

  // ---- per-lane constant LDS fragment offsets (R6/R7-verified in-lane-P map) ----
  const int rbase=8*(l16>>2)+(l16&3);
  const int swk=(l16&3)|(((l16>>2)&1)<<2);  // = swz(ka row), nt-independent
  const int swv=(l16&3)|(((l16>>3)&1)<<2);  // = swz(vb row), dt-independent
  int kaoff[2][4], vboff[2][4];
  #pragma unroll
  for(int kk=0;kk<2;++kk){
    #pragma unroll
    for(int nt=0;nt<4;++nt)
      kaoff[kk][nt]=(rbase+(nt&1)*4+(nt>>1)*32)*64+(((quad+4*kk)^swk)*8);
    #pragma unroll
    for(int dt=0;dt<4;++dt)
      vboff[kk][dt]=(dt*16+l16)*64+(((quad+4*kk)^swv)*8);
  }

  // ---- staging geometry (512 thr cover one 64x64 tile each for K and V) ----
  const int kr=tid>>3, klc=tid&7;                 // K: row, logical chunk
  const int kwaddr=kr*64+((klc^swz(kr))*8);       // swizzled write addr (shorts)
  const int vw=tid>>6, vd=tid&63;                 // V: key-chunk, d-column
  const int vwaddr=vd*64+((vw^swz(vd))*8);
  const float* kg=k+base;
  const float* vg=v+base;

  f32x4 oacc[4];
  #pragma unroll
  for(int dt=0;dt<4;++dt) oacc[dt]=(f32x4){0.f,0.f,0.f,0.f};
  float lrun=0.f;

  const int Tb =2*mt+1;
  const int Tlo=(2*mt>8)?(2*mt-8):0;
  const int myTb=2*mt+h;
  const bool clip=(myTb>=8);
  const int myTlo=clip?(myTb-8):0;

  // ---- stage tile Tlo -> buf0 ----
  {
    const float* kt=kg+(long)Tlo*4096;
    const float* vt=vg+(long)Tlo*4096;
    float4 kf0=*(const float4*)(kt+kr*64+klc*8);
    float4 kf1=*(const float4*)(kt+kr*64+klc*8+4);
    float vf[8];
    #pragma unroll
    for(int j=0;j<8;++j) vf[j]=vt[(vw*8+j)*64+vd];
    unsigned short hk[8];
    hk[0]=f2bf(kf0.x); hk[1]=f2bf(kf0.y); hk[2]=f2bf(kf0.z); hk[3]=f2bf(kf0.w);
    hk[4]=f2bf(kf1.x); hk[5]=f2bf(kf1.y); hk[6]=f2bf(kf1.z); hk[7]=f2bf(kf1.w);
    *(uint4*)&Ks[0][kwaddr]=*(uint4*)hk;
    unsigned short hv[8];
    #pragma unroll
    for(int j=0;j<8;++j) hv[j]=f2bf(vf[j]);
    *(uint4*)&Vsh[0][vwaddr]=*(uint4*)hv;
  }
  __syncthreads();

  for(int t=Tlo;t<=Tb;++t){
    const int buf=(t-Tlo)&1;
    const bool pf=(t<Tb);

    // ---- issue global prefetch for tile t+1 (latency hides under compute) ----
    float4 kf0,kf1; float vf[8];
    if(pf){
      const float* kt=kg+(long)(t+1)*4096;
      const float* vt=vg+(long)(t+1)*4096;
      kf0=*(const float4*)(kt+kr*64+klc*8);
      kf1=*(const float4*)(kt+kr*64+klc*8+4);
      #pragma unroll
      for(int j=0;j<8;++j) vf[j]=vt[(vw*8+j)*64+vd];
    }

    if(t>=myTlo && t<=myTb){                // wave-uniform tile skip
      // ---- S^T = K Q^T ----
      f32x4 sacc[4];
      #pragma unroll
      for(int nt=0;nt<4;++nt) sacc[nt]=(f32x4){0.f,0.f,0.f,0.f};
      #pragma unroll
      for(int kk=0;kk<2;++kk)
        #pragma unroll
        for(int nt=0;nt<4;++nt){
          short8 ka=*(const short8*)&Ks[buf][kaoff[kk][nt]];
          sacc[nt]=__builtin_amdgcn_mfma_f32_16x16x32_bf16(ka,qa[kk],sacc[nt],0,0,0);
        }

      // ---- p = exp2(s); mask only on boundary tiles; trunc-pack (in-lane) ----
      unsigned pp[8];
      float ls=0.f;
      const bool msk=(t==myTb)||(clip&&t==myTlo);
      #pragma unroll
      for(int nt=0;nt<4;++nt){
        float e0=__builtin_amdgcn_exp2f(sacc[nt][0]);
        float e1=__builtin_amdgcn_exp2f(sacc[nt][1]);
        float e2=__builtin_amdgcn_exp2f(sacc[nt][2]);
        float e3=__builtin_amdgcn_exp2f(sacc[nt][3]);
        if(msk){
          const int kb0=t*64+8*quad+(nt&1)*4+(nt>>1)*32;
          e0=((kb0+0<=qrow)&&(kb0+0+511>=qrow))?e0:0.f;
          e1=((kb0+1<=qrow)&&(kb0+1+511>=qrow))?e1:0.f;
          e2=((kb0+2<=qrow)&&(kb0+2+511>=qrow))?e2:0.f;
          e3=((kb0+3<=qrow)&&(kb0+3+511>=qrow))?e3:0.f;
        }
        ls+=e0+e1+e2+e3;
        pp[nt*2+0]=(__float_as_uint(e1)&0xFFFF0000u)|(__float_as_uint(e0)>>16);
        pp[nt*2+1]=(__float_as_uint(e3)&0xFFFF0000u)|(__float_as_uint(e2)>>16);
      }
      lrun+=ls;
      i32x4 i0={(int)pp[0],(int)pp[1],(int)pp[2],(int)pp[3]};
      i32x4 i1={(int)pp[4],(int)pp[5],(int)pp[6],(int)pp[7]};
      short8 pa0=*(short8*)&i0;
      short8 pa1=*(short8*)&i1;

      // ---- O += P V ----
      #pragma unroll
      for(int dt=0;dt<4;++dt){
        short8 vb0=*(const short8*)&Vsh[buf][vboff[0][dt]];
        short8 vb1=*(const short8*)&Vsh[buf][vboff[1][dt]];
        oacc[dt]=__builtin_amdgcn_mfma_f32_16x16x32_bf16(pa0,vb0,oacc[dt],0,0,0);
        oacc[dt]=__builtin_amdgcn_mfma_f32_16x16x32_bf16(pa1,vb1,oacc[dt],0,0,0);
      }
    }

    // ---- convert + write prefetched tile into the other buffer ----
    if(pf){
      unsigned short hk[8];
      hk[0]=f2bf(kf0.x); hk[1]=f2bf(kf0.y); hk[2]=f2bf(kf0.z); hk[3]=f2bf(kf0.w);
      hk[4]=f2bf(kf1.x); hk[5]=f2bf(kf1.y); hk[6]=f2bf(kf1.z); hk[7]=f2bf(kf1.w);
      *(uint4*)&Ks[buf^1][kwaddr]=*(uint4*)hk;
      unsigned short hv[8];
      #pragma unroll
      for(int j=0;j<8;++j) hv[j]=f2bf(vf[j]);
      *(uint4*)&Vsh[buf^1][vwaddr]=*(uint4*)hv;
    }
    __syncthreads();
  }

  // ---- epilogue: l = sum over the 4 quads (disjoint key subsets per quad) ----
  lrun+=__shfl_xor(lrun,16);
  lrun+=__shfl_xor(lrun,32);
  float linv=1.0f/lrun;                     // diagonal always contributes > 0
  #pragma unroll
  for(int r=0;r<4;++r){
    float lr=__shfl(linv,quad*4+r);         // lane (quad*4+r) holds that row's l
    const int orow=m0+wv*16+quad*4+r;
    #pragma unroll
    for(int dt=0;dt<4;++dt)
      out[base+(long)orow*HD+dt*16+l16]=oacc[dt][r]*lr;
  }
}

extern "C" void kernel_launch(void* const* d_in, const int* in_sizes, int n_in,
                              void* d_out, int out_size, void* d_ws, size_t ws_size,
                              hipStream_t stream) {
  (void)in_sizes; (void)n_in; (void)out_size; (void)d_ws; (void)ws_size;
  const float* q=(const float*)d_in[0];
  const float* k=(const float*)d_in[1];
  const float* v=(const float*)d_in[2];
  float* o=(float*)d_out;
  hipLaunchKernelGGL(swa_fused, dim3(512), dim3(512), 0, stream, q, k, v, o);
}